// Round 1
// baseline (368.253 us; speedup 1.0000x reference)
//
#include <hip/hip_runtime.h>
#include <hip/hip_bf16.h>

typedef __attribute__((ext_vector_type(8))) short bf16x8;
typedef __attribute__((ext_vector_type(4))) float f32x4;
typedef __attribute__((ext_vector_type(4))) unsigned short us4;

#define B_ 4
#define S_ 2048
#define E_ 1024
#define H_ 1024
#define M_ (B_ * S_)   // 8192 tokens
#define N3_ (3 * H_)   // 3072 fused QKV columns

__device__ __forceinline__ unsigned short f2bf(float f) {
  union { float f; unsigned u; } v; v.f = f;
  unsigned r = v.u + 0x7fffu + ((v.u >> 16) & 1u);  // RNE
  return (unsigned short)(r >> 16);
}

// ---------------- K0a: x fp32 -> bf16 (vectorized) ----------------
__global__ __launch_bounds__(256) void k_convert_x(const float* __restrict__ x,
                                                   unsigned short* __restrict__ xb) {
  int i = blockIdx.x * 256 + threadIdx.x;  // one float4 per thread
  const float4 v = reinterpret_cast<const float4*>(x)[i];
  us4 o;
  o[0] = f2bf(v.x); o[1] = f2bf(v.y); o[2] = f2bf(v.z); o[3] = f2bf(v.w);
  reinterpret_cast<us4*>(xb)[i] = o;
}

// ------- K0b: W[E][H] fp32 -> Wt[3H][E] bf16 (transposed, LDS tile) -------
__global__ __launch_bounds__(256) void k_transpose_w(const float* __restrict__ Wq,
                                                     const float* __restrict__ Wk,
                                                     const float* __restrict__ Wv,
                                                     unsigned short* __restrict__ Wt) {
  __shared__ float tile[32][33];
  const int mat = blockIdx.z;
  const float* W = (mat == 0) ? Wq : (mat == 1) ? Wk : Wv;
  const int n0 = blockIdx.x * 32, k0 = blockIdx.y * 32;
  const int tx = threadIdx.x, ty = threadIdx.y;
#pragma unroll
  for (int i = 0; i < 32; i += 8)
    tile[ty + i][tx] = W[(size_t)(k0 + ty + i) * H_ + n0 + tx];
  __syncthreads();
#pragma unroll
  for (int i = 0; i < 32; i += 8) {
    int n = n0 + ty + i;
    Wt[(size_t)(mat * H_ + n) * E_ + k0 + tx] = f2bf(tile[tx][ty + i]);
  }
}

// ---------------- K1: fused QKV GEMM (bf16 MFMA, 128x128x64) ----------------
// C[m,n] = xb[m,:] . Wt[n,:] + bias[n]; writes Q,K row-major bf16, V transposed.
__global__ __launch_bounds__(256, 2) void k_gemm_qkv(
    const unsigned short* __restrict__ xb, const unsigned short* __restrict__ Wt,
    const float* __restrict__ bq, const float* __restrict__ bk,
    const float* __restrict__ bv,
    unsigned short* __restrict__ Qb, unsigned short* __restrict__ Kb,
    unsigned short* __restrict__ Vt) {
  __shared__ unsigned short As[128 * 64];
  __shared__ unsigned short Bs[128 * 64];
  const int nwg = gridDim.x;      // 1536, %8==0 -> bijective XCD swizzle
  const int cpx = nwg >> 3;
  int bid = blockIdx.x;
  bid = (bid & 7) * cpx + (bid >> 3);
  const int tm = bid / 24, tn = bid % 24;
  const int gm = tm * 128, gn = tn * 128;
  const int tid = threadIdx.x, w = tid >> 6, lane = tid & 63;
  const int wr = w >> 1, wc = w & 1;
  const int srow = lane >> 3;                // row within 8-row store group
  const int schunk = (lane & 7) ^ srow;      // pre-swizzled source 16B chunk

  f32x4 acc[4][4];
#pragma unroll
  for (int i = 0; i < 4; ++i)
#pragma unroll
    for (int j = 0; j < 4; ++j) acc[i][j] = (f32x4)0.0f;

  for (int kt = 0; kt < 16; ++kt) {
    const int k0 = kt * 64;
#pragma unroll
    for (int i = 0; i < 4; ++i) {
      const int row = w * 32 + i * 8 + srow;
      __builtin_amdgcn_global_load_lds(
          (const __attribute__((address_space(1))) unsigned int*)(xb + (size_t)(gm + row) * E_ + k0 + schunk * 8),
          (__attribute__((address_space(3))) unsigned int*)(As + (w * 32 + i * 8) * 64),
          16, 0, 0);
    }
#pragma unroll
    for (int i = 0; i < 4; ++i) {
      const int row = w * 32 + i * 8 + srow;
      __builtin_amdgcn_global_load_lds(
          (const __attribute__((address_space(1))) unsigned int*)(Wt + (size_t)(gn + row) * E_ + k0 + schunk * 8),
          (__attribute__((address_space(3))) unsigned int*)(Bs + (w * 32 + i * 8) * 64),
          16, 0, 0);
    }
    __syncthreads();
#pragma unroll
    for (int ks = 0; ks < 2; ++ks) {
      bf16x8 af[4], bfrag[4];
#pragma unroll
      for (int mt = 0; mt < 4; ++mt) {
        const int r16 = wr * 64 + mt * 16 + (lane & 15);
        const int ch = (ks * 4 + (lane >> 4)) ^ (r16 & 7);
        af[mt] = *reinterpret_cast<const bf16x8*>(&As[r16 * 64 + ch * 8]);
      }
#pragma unroll
      for (int nt = 0; nt < 4; ++nt) {
        const int c16 = wc * 64 + nt * 16 + (lane & 15);
        const int ch = (ks * 4 + (lane >> 4)) ^ (c16 & 7);
        bfrag[nt] = *reinterpret_cast<const bf16x8*>(&Bs[c16 * 64 + ch * 8]);
      }
#pragma unroll
      for (int mt = 0; mt < 4; ++mt)
#pragma unroll
        for (int nt = 0; nt < 4; ++nt)
          acc[mt][nt] = __builtin_amdgcn_mfma_f32_16x16x32_bf16(
              af[mt], bfrag[nt], acc[mt][nt], 0, 0, 0);
    }
    __syncthreads();
  }

  // epilogue: bias add, bf16 convert, scatter to Q/K (row-major) or Vt (transposed)
  const int matid = gn >> 10;  // 0=Q, 1=K, 2=V (uniform per block)
  const float* bias = (matid == 0) ? bq : (matid == 1) ? bk : bv;
#pragma unroll
  for (int mt = 0; mt < 4; ++mt) {
#pragma unroll
    for (int nt = 0; nt < 4; ++nt) {
      const int row0 = gm + wr * 64 + mt * 16 + (lane >> 4) * 4;
      const int col = gn + wc * 64 + nt * 16 + (lane & 15);
      const int h = col & 1023;
      const float bb = bias[h];
      if (matid < 2) {
        unsigned short* dst = matid ? Kb : Qb;
#pragma unroll
        for (int r = 0; r < 4; ++r)
          dst[(size_t)(row0 + r) * H_ + h] = f2bf(acc[mt][nt][r] + bb);
      } else {
        const int bat = row0 >> 11, s0 = row0 & 2047;
        us4 pk;
#pragma unroll
        for (int r = 0; r < 4; ++r) pk[r] = f2bf(acc[mt][nt][r] + bb);
        *reinterpret_cast<us4*>(&Vt[(size_t)bat * H_ * S_ + (size_t)h * S_ + s0]) = pk;
      }
    }
  }
}

// ---------------- K2: causal flash attention, d-split across 8 waves ----------------
// wg = (batch, 32-row q tile). Wave w owns d in [128w,128w+128). KBLK=64.
__global__ __launch_bounds__(512, 2) void k_flash(
    const unsigned short* __restrict__ Qb, const unsigned short* __restrict__ Kb,
    const unsigned short* __restrict__ Vt, float* __restrict__ out) {
  // [ (w*4+nt)*2+mt ][260] padded f32 partial-score blocks (64 x 260)
  __shared__ float S_lds[64 * 260];
  __shared__ unsigned short P_lds[32 * 72];  // [32 rows][72] padded bf16
  __shared__ __align__(16) float m_lds[32];
  __shared__ __align__(16) float l_lds[32];
  __shared__ __align__(16) float alpha_lds[32];

  const int tid = threadIdx.x, w = tid >> 6, lane = tid & 63;
  const int batch = blockIdx.x >> 6;
  const int t = blockIdx.x & 63;
  const int q0 = t * 32;
  const float scale = 0.03125f;  // 1/sqrt(1024)

  // Q fragments in registers: [mt][kd], A-layout (row=lane&15, k=(lane>>4)*8+j)
  bf16x8 qf[2][4];
#pragma unroll
  for (int mt = 0; mt < 2; ++mt) {
    const size_t qrow = (size_t)(batch * S_ + q0 + mt * 16 + (lane & 15));
#pragma unroll
    for (int kd = 0; kd < 4; ++kd)
      qf[mt][kd] = *reinterpret_cast<const bf16x8*>(
          &Qb[qrow * H_ + w * 128 + kd * 32 + (lane >> 4) * 8]);
  }
  f32x4 acco[2][8];
#pragma unroll
  for (int mt = 0; mt < 2; ++mt)
#pragma unroll
    for (int nd = 0; nd < 8; ++nd) acco[mt][nd] = (f32x4)0.0f;
  if (tid < 32) { m_lds[tid] = -1e30f; l_lds[tid] = 0.0f; }
  __syncthreads();

  const int kend = q0 + 32;
  for (int k0 = 0; k0 < kend; k0 += 64) {
    // -------- Phase A: partial QK^T over this wave's 128-d slice --------
    f32x4 accs[2][4];
#pragma unroll
    for (int mt = 0; mt < 2; ++mt)
#pragma unroll
      for (int nt = 0; nt < 4; ++nt) accs[mt][nt] = (f32x4)0.0f;
#pragma unroll
    for (int nt = 0; nt < 4; ++nt) {
      bf16x8 kf[4];
#pragma unroll
      for (int kd = 0; kd < 4; ++kd)
        kf[kd] = *reinterpret_cast<const bf16x8*>(
            &Kb[(size_t)(batch * S_ + k0 + nt * 16 + (lane & 15)) * H_ +
                w * 128 + kd * 32 + (lane >> 4) * 8]);
#pragma unroll
      for (int mt = 0; mt < 2; ++mt)
#pragma unroll
        for (int kd = 0; kd < 4; ++kd)
          accs[mt][nt] = __builtin_amdgcn_mfma_f32_16x16x32_bf16(
              qf[mt][kd], kf[kd], accs[mt][nt], 0, 0, 0);
    }
#pragma unroll
    for (int mt = 0; mt < 2; ++mt)
#pragma unroll
      for (int nt = 0; nt < 4; ++nt)
        *reinterpret_cast<f32x4*>(
            &S_lds[((w * 4 + nt) * 2 + mt) * 260 + lane * 4]) = accs[mt][nt];
    __syncthreads();

    // -------- Phase B: reduce 8 partials, mask, online softmax, P->LDS --------
    {
      const int r = tid >> 4;            // 0..31 q-row
      const int c0 = (tid & 15) * 4;     // 4 consecutive key columns
      const int mt = r >> 4, row16 = r & 15, reg = r & 3;
      float s[4];
#pragma unroll
      for (int j = 0; j < 4; ++j) {
        const int c = c0 + j;
        const int nt = c >> 4;
        const int lw = (c & 15) + ((row16 >> 2) << 4);
        float acc = 0.f;
#pragma unroll
        for (int w2 = 0; w2 < 8; ++w2)
          acc += S_lds[((w2 * 4 + nt) * 2 + mt) * 260 + lw * 4 + reg];
        acc *= scale;
        if (k0 + c > q0 + r) acc = -1e30f;  // causal mask
        s[j] = acc;
      }
      float mx = fmaxf(fmaxf(s[0], s[1]), fmaxf(s[2], s[3]));
#pragma unroll
      for (int off = 8; off; off >>= 1) mx = fmaxf(mx, __shfl_xor(mx, off));
      const float mold = m_lds[r];
      const float mnew = fmaxf(mold, mx);
      const float alpha = __expf(mold - mnew);
      float p[4], rs = 0.f;
#pragma unroll
      for (int j = 0; j < 4; ++j) { p[j] = __expf(s[j] - mnew); rs += p[j]; }
#pragma unroll
      for (int off = 8; off; off >>= 1) rs += __shfl_xor(rs, off);
      if ((tid & 15) == 0) {
        m_lds[r] = mnew;
        l_lds[r] = l_lds[r] * alpha + rs;
        alpha_lds[r] = alpha;
      }
      us4 pk;
#pragma unroll
      for (int j = 0; j < 4; ++j) pk[j] = f2bf(p[j]);
      *reinterpret_cast<us4*>(&P_lds[r * 72 + c0]) = pk;
    }
    __syncthreads();

    // -------- Phase C: rescale O, PV MFMA over this wave's d slice --------
    {
      f32x4 al[2];
#pragma unroll
      for (int mt = 0; mt < 2; ++mt)
        al[mt] = *reinterpret_cast<const f32x4*>(&alpha_lds[mt * 16 + (lane >> 4) * 4]);
#pragma unroll
      for (int mt = 0; mt < 2; ++mt)
#pragma unroll
        for (int nd = 0; nd < 8; ++nd)
#pragma unroll
          for (int j = 0; j < 4; ++j) acco[mt][nd][j] *= al[mt][j];
      bf16x8 pa[2][2];
#pragma unroll
      for (int mt = 0; mt < 2; ++mt)
#pragma unroll
        for (int kk = 0; kk < 2; ++kk)
          pa[mt][kk] = *reinterpret_cast<const bf16x8*>(
              &P_lds[(mt * 16 + (lane & 15)) * 72 + kk * 32 + (lane >> 4) * 8]);
#pragma unroll
      for (int nd = 0; nd < 8; ++nd) {
        bf16x8 vb[2];
#pragma unroll
        for (int kk = 0; kk < 2; ++kk)
          vb[kk] = *reinterpret_cast<const bf16x8*>(
              &Vt[(size_t)batch * H_ * S_ +
                  (size_t)(w * 128 + nd * 16 + (lane & 15)) * S_ +
                  k0 + kk * 32 + (lane >> 4) * 8]);
#pragma unroll
        for (int mt = 0; mt < 2; ++mt)
#pragma unroll
          for (int kk = 0; kk < 2; ++kk)
            acco[mt][nd] = __builtin_amdgcn_mfma_f32_16x16x32_bf16(
                pa[mt][kk], vb[kk], acco[mt][nd], 0, 0, 0);
      }
    }
  }

  // -------- epilogue: divide by l, store fp32 --------
  {
#pragma unroll
    for (int mt = 0; mt < 2; ++mt) {
      const f32x4 lf = *reinterpret_cast<const f32x4*>(&l_lds[mt * 16 + (lane >> 4) * 4]);
#pragma unroll
      for (int nd = 0; nd < 8; ++nd) {
#pragma unroll
        for (int reg = 0; reg < 4; ++reg) {
          const int srow = q0 + mt * 16 + (lane >> 4) * 4 + reg;
          out[(size_t)batch * S_ * H_ + (size_t)srow * H_ +
              w * 128 + nd * 16 + (lane & 15)] = acco[mt][nd][reg] / lf[reg];
        }
      }
    }
  }
}

extern "C" void kernel_launch(void* const* d_in, const int* in_sizes, int n_in,
                              void* d_out, int out_size, void* d_ws, size_t ws_size,
                              hipStream_t stream) {
  const float* x  = (const float*)d_in[0];
  const float* Wq = (const float*)d_in[1];
  const float* bq = (const float*)d_in[2];
  const float* Wk = (const float*)d_in[3];
  const float* bk = (const float*)d_in[4];
  const float* Wv = (const float*)d_in[5];
  const float* bv = (const float*)d_in[6];
  float* out = (float*)d_out;

  // workspace layout (bf16): xb 16MB | Wt 6MB | Qb 16MB | Kb 16MB | Vt 16MB = 70MB
  unsigned short* xb = (unsigned short*)d_ws;
  unsigned short* Wt = xb + (size_t)M_ * E_;
  unsigned short* Qb = Wt + (size_t)N3_ * E_;
  unsigned short* Kb = Qb + (size_t)M_ * H_;
  unsigned short* Vt = Kb + (size_t)M_ * H_;

  hipLaunchKernelGGL(k_convert_x, dim3(M_ * E_ / 1024), dim3(256), 0, stream, x, xb);
  hipLaunchKernelGGL(k_transpose_w, dim3(32, 32, 3), dim3(32, 8), 0, stream, Wq, Wk, Wv, Wt);
  hipLaunchKernelGGL(k_gemm_qkv, dim3(1536), dim3(256), 0, stream,
                     xb, Wt, bq, bk, bv, Qb, Kb, Vt);
  hipLaunchKernelGGL(k_flash, dim3(256), dim3(512), 0, stream, Qb, Kb, Vt, out);
}

// Round 2
// 159.958 us; speedup vs baseline: 2.3022x; 2.3022x over previous
//
#include <hip/hip_runtime.h>
#include <hip/hip_bf16.h>

typedef __attribute__((ext_vector_type(8))) short bf16x8;
typedef __attribute__((ext_vector_type(4))) float f32x4;
typedef __attribute__((ext_vector_type(4))) unsigned short us4;

#define B_ 4
#define S_ 2048
#define E_ 1024
#define H_ 1024
#define M_ (B_ * S_)   // 8192 tokens
#define N3_ (3 * H_)   // 3072 fused QKV columns
#define NTILE_ 16      // 2048/128 tiles per side
#define NTRI_ 136      // lower-tri tiles per batch (16*17/2)

__device__ __forceinline__ unsigned short f2bf(float f) {
  union { float f; unsigned u; } v; v.f = f;
  unsigned r = v.u + 0x7fffu + ((v.u >> 16) & 1u);  // RNE
  return (unsigned short)(r >> 16);
}
__device__ __forceinline__ float bf2f(unsigned short u) {
  union { unsigned u; float f; } v; v.u = ((unsigned)u) << 16; return v.f;
}

// ---------------- K0a: x fp32 -> bf16 (vectorized) ----------------
__global__ __launch_bounds__(256) void k_convert_x(const float* __restrict__ x,
                                                   unsigned short* __restrict__ xb) {
  int i = blockIdx.x * 256 + threadIdx.x;  // one float4 per thread
  const float4 v = reinterpret_cast<const float4*>(x)[i];
  us4 o;
  o[0] = f2bf(v.x); o[1] = f2bf(v.y); o[2] = f2bf(v.z); o[3] = f2bf(v.w);
  reinterpret_cast<us4*>(xb)[i] = o;
}

// ------- K0b: W[E][H] fp32 -> Wt[3H][E] bf16 (transposed, LDS tile) -------
__global__ __launch_bounds__(256) void k_transpose_w(const float* __restrict__ Wq,
                                                     const float* __restrict__ Wk,
                                                     const float* __restrict__ Wv,
                                                     unsigned short* __restrict__ Wt) {
  __shared__ float tile[32][33];
  const int mat = blockIdx.z;
  const float* W = (mat == 0) ? Wq : (mat == 1) ? Wk : Wv;
  const int n0 = blockIdx.x * 32, k0 = blockIdx.y * 32;
  const int tx = threadIdx.x, ty = threadIdx.y;
#pragma unroll
  for (int i = 0; i < 32; i += 8)
    tile[ty + i][tx] = W[(size_t)(k0 + ty + i) * H_ + n0 + tx];
  __syncthreads();
#pragma unroll
  for (int i = 0; i < 32; i += 8) {
    int n = n0 + ty + i;
    Wt[(size_t)(mat * H_ + n) * E_ + k0 + tx] = f2bf(tile[tx][ty + i]);
  }
}

// ---------------- K1: fused QKV GEMM (bf16 MFMA, 128x128x64) ----------------
__global__ __launch_bounds__(256, 2) void k_gemm_qkv(
    const unsigned short* __restrict__ xb, const unsigned short* __restrict__ Wt,
    const float* __restrict__ bq, const float* __restrict__ bk,
    const float* __restrict__ bv,
    unsigned short* __restrict__ Qb, unsigned short* __restrict__ Kb,
    unsigned short* __restrict__ Vt) {
  __shared__ unsigned short As[128 * 64];
  __shared__ unsigned short Bs[128 * 64];
  const int nwg = gridDim.x;      // 1536, %8==0 -> bijective XCD swizzle
  const int cpx = nwg >> 3;
  int bid = blockIdx.x;
  bid = (bid & 7) * cpx + (bid >> 3);
  const int tm = bid / 24, tn = bid % 24;
  const int gm = tm * 128, gn = tn * 128;
  const int tid = threadIdx.x, w = tid >> 6, lane = tid & 63;
  const int wr = w >> 1, wc = w & 1;
  const int srow = lane >> 3;                // row within 8-row store group
  const int schunk = (lane & 7) ^ srow;      // pre-swizzled source 16B chunk

  f32x4 acc[4][4];
#pragma unroll
  for (int i = 0; i < 4; ++i)
#pragma unroll
    for (int j = 0; j < 4; ++j) acc[i][j] = (f32x4)0.0f;

  for (int kt = 0; kt < 16; ++kt) {
    const int k0 = kt * 64;
#pragma unroll
    for (int i = 0; i < 4; ++i) {
      const int row = w * 32 + i * 8 + srow;
      __builtin_amdgcn_global_load_lds(
          (const __attribute__((address_space(1))) unsigned int*)(xb + (size_t)(gm + row) * E_ + k0 + schunk * 8),
          (__attribute__((address_space(3))) unsigned int*)(As + (w * 32 + i * 8) * 64),
          16, 0, 0);
    }
#pragma unroll
    for (int i = 0; i < 4; ++i) {
      const int row = w * 32 + i * 8 + srow;
      __builtin_amdgcn_global_load_lds(
          (const __attribute__((address_space(1))) unsigned int*)(Wt + (size_t)(gn + row) * E_ + k0 + schunk * 8),
          (__attribute__((address_space(3))) unsigned int*)(Bs + (w * 32 + i * 8) * 64),
          16, 0, 0);
    }
    __syncthreads();
#pragma unroll
    for (int ks = 0; ks < 2; ++ks) {
      bf16x8 af[4], bfrag[4];
#pragma unroll
      for (int mt = 0; mt < 4; ++mt) {
        const int r16 = wr * 64 + mt * 16 + (lane & 15);
        const int ch = (ks * 4 + (lane >> 4)) ^ (r16 & 7);
        af[mt] = *reinterpret_cast<const bf16x8*>(&As[r16 * 64 + ch * 8]);
      }
#pragma unroll
      for (int nt = 0; nt < 4; ++nt) {
        const int c16 = wc * 64 + nt * 16 + (lane & 15);
        const int ch = (ks * 4 + (lane >> 4)) ^ (c16 & 7);
        bfrag[nt] = *reinterpret_cast<const bf16x8*>(&Bs[c16 * 64 + ch * 8]);
      }
#pragma unroll
      for (int mt = 0; mt < 4; ++mt)
#pragma unroll
        for (int nt = 0; nt < 4; ++nt)
          acc[mt][nt] = __builtin_amdgcn_mfma_f32_16x16x32_bf16(
              af[mt], bfrag[nt], acc[mt][nt], 0, 0, 0);
    }
    __syncthreads();
  }

  const int matid = gn >> 10;  // 0=Q, 1=K, 2=V (uniform per block)
  const float* bias = (matid == 0) ? bq : (matid == 1) ? bk : bv;
#pragma unroll
  for (int mt = 0; mt < 4; ++mt) {
#pragma unroll
    for (int nt = 0; nt < 4; ++nt) {
      const int row0 = gm + wr * 64 + mt * 16 + (lane >> 4) * 4;
      const int col = gn + wc * 64 + nt * 16 + (lane & 15);
      const int h = col & 1023;
      const float bb = bias[h];
      if (matid < 2) {
        unsigned short* dst = matid ? Kb : Qb;
#pragma unroll
        for (int r = 0; r < 4; ++r)
          dst[(size_t)(row0 + r) * H_ + h] = f2bf(acc[mt][nt][r] + bb);
      } else {
        const int bat = row0 >> 11, s0 = row0 & 2047;
        us4 pk;
#pragma unroll
        for (int r = 0; r < 4; ++r) pk[r] = f2bf(acc[mt][nt][r] + bb);
        *reinterpret_cast<us4*>(&Vt[(size_t)bat * H_ * S_ + (size_t)h * S_ + s0]) = pk;
      }
    }
  }
}

// ------- K2: scores GEMM, lower-triangular tiles only, packed output -------
// S[q,k] = (Q[q,:].K[k,:]) * 1/32, stored bf16 into packed tri-tile layout:
// tile (tm,tn), tn<=tm at [(batch*136 + tm(tm+1)/2 + tn)*16384], 128x128 row-major.
__global__ __launch_bounds__(256, 2) void k_gemm_scores(
    const unsigned short* __restrict__ Qb, const unsigned short* __restrict__ Kb,
    unsigned short* __restrict__ Pt) {
  __shared__ unsigned short As[128 * 64];
  __shared__ unsigned short Bs[128 * 64];
  const int bid = blockIdx.x;
  const int batch = bid >> 8, t = bid & 255;
  const int tm = t >> 4, tn = t & 15;
  if (tn > tm) return;  // upper tiles never needed
  const int gm = tm * 128, gn = tn * 128;
  const int tid = threadIdx.x, w = tid >> 6, lane = tid & 63;
  const int wr = w >> 1, wc = w & 1;
  const int srow = lane >> 3;
  const int schunk = (lane & 7) ^ srow;
  const unsigned short* Abase = Qb + (size_t)batch * S_ * H_;
  const unsigned short* Bbase = Kb + (size_t)batch * S_ * H_;

  f32x4 acc[4][4];
#pragma unroll
  for (int i = 0; i < 4; ++i)
#pragma unroll
    for (int j = 0; j < 4; ++j) acc[i][j] = (f32x4)0.0f;

  for (int kt = 0; kt < 16; ++kt) {
    const int k0 = kt * 64;
#pragma unroll
    for (int i = 0; i < 4; ++i) {
      const int row = w * 32 + i * 8 + srow;
      __builtin_amdgcn_global_load_lds(
          (const __attribute__((address_space(1))) unsigned int*)(Abase + (size_t)(gm + row) * H_ + k0 + schunk * 8),
          (__attribute__((address_space(3))) unsigned int*)(As + (w * 32 + i * 8) * 64),
          16, 0, 0);
      __builtin_amdgcn_global_load_lds(
          (const __attribute__((address_space(1))) unsigned int*)(Bbase + (size_t)(gn + row) * H_ + k0 + schunk * 8),
          (__attribute__((address_space(3))) unsigned int*)(Bs + (w * 32 + i * 8) * 64),
          16, 0, 0);
    }
    __syncthreads();
#pragma unroll
    for (int ks = 0; ks < 2; ++ks) {
      bf16x8 af[4], bfrag[4];
#pragma unroll
      for (int mt = 0; mt < 4; ++mt) {
        const int r16 = wr * 64 + mt * 16 + (lane & 15);
        const int ch = (ks * 4 + (lane >> 4)) ^ (r16 & 7);
        af[mt] = *reinterpret_cast<const bf16x8*>(&As[r16 * 64 + ch * 8]);
      }
#pragma unroll
      for (int nt = 0; nt < 4; ++nt) {
        const int c16 = wc * 64 + nt * 16 + (lane & 15);
        const int ch = (ks * 4 + (lane >> 4)) ^ (c16 & 7);
        bfrag[nt] = *reinterpret_cast<const bf16x8*>(&Bs[c16 * 64 + ch * 8]);
      }
#pragma unroll
      for (int mt = 0; mt < 4; ++mt)
#pragma unroll
        for (int nt = 0; nt < 4; ++nt)
          acc[mt][nt] = __builtin_amdgcn_mfma_f32_16x16x32_bf16(
              af[mt], bfrag[nt], acc[mt][nt], 0, 0, 0);
    }
    __syncthreads();
  }

  const size_t tbase = ((size_t)batch * NTRI_ + (tm * (tm + 1)) / 2 + tn) * 16384;
#pragma unroll
  for (int mt = 0; mt < 4; ++mt) {
#pragma unroll
    for (int nt = 0; nt < 4; ++nt) {
      const int row0 = wr * 64 + mt * 16 + (lane >> 4) * 4;
      const int col = wc * 64 + nt * 16 + (lane & 15);
#pragma unroll
      for (int r = 0; r < 4; ++r)
        Pt[tbase + (size_t)(row0 + r) * 128 + col] = f2bf(acc[mt][nt][r] * 0.03125f);
    }
  }
}

// ------- K3: in-place causal row softmax over packed tri tiles -------
// One wave per row. Row q valid cols [0,q]; writes 0 for (q, W) pad, W=(tm+1)*128.
__global__ __launch_bounds__(256) void k_softmax(unsigned short* __restrict__ Pt) {
  const int tid = threadIdx.x, lane = tid & 63;
  const int gr = blockIdx.x * 4 + (tid >> 6);
  const int batch = gr >> 11, q = gr & 2047;
  const int tm = q >> 7, r = q & 127;
  const int W = (tm + 1) << 7;
  const size_t rowb = ((size_t)batch * NTRI_ + (tm * (tm + 1)) / 2) * 16384 + (size_t)r * 128;

  float s[32];
  float mx = -1e30f;
#pragma unroll
  for (int it = 0; it < 4; ++it) {
    const int c = it * 512 + lane * 8;
    if (c < W) {
      const int tn = c >> 7;
      const bf16x8 v = *reinterpret_cast<const bf16x8*>(&Pt[rowb + (size_t)tn * 16384 + (c & 127)]);
#pragma unroll
      for (int j = 0; j < 8; ++j) {
        float f = bf2f((unsigned short)v[j]);
        if (c + j > q) f = -1e30f;  // causal mask
        s[it * 8 + j] = f;
        mx = fmaxf(mx, f);
      }
    } else {
#pragma unroll
      for (int j = 0; j < 8; ++j) s[it * 8 + j] = -1e30f;
    }
  }
#pragma unroll
  for (int off = 32; off; off >>= 1) mx = fmaxf(mx, __shfl_xor(mx, off));
  float sum = 0.f;
#pragma unroll
  for (int it = 0; it < 4; ++it)
#pragma unroll
    for (int j = 0; j < 8; ++j) {
      const float p = __expf(s[it * 8 + j] - mx);
      s[it * 8 + j] = p;
      sum += p;
    }
#pragma unroll
  for (int off = 32; off; off >>= 1) sum += __shfl_xor(sum, off);
  const float inv = 1.0f / sum;
#pragma unroll
  for (int it = 0; it < 4; ++it) {
    const int c = it * 512 + lane * 8;
    if (c < W) {
      const int tn = c >> 7;
      bf16x8 o;
#pragma unroll
      for (int j = 0; j < 8; ++j) o[j] = (short)f2bf(s[it * 8 + j] * inv);
      *reinterpret_cast<bf16x8*>(&Pt[rowb + (size_t)tn * 16384 + (c & 127)]) = o;
    }
  }
}

// ------- K4: O = P.V GEMM, variable-K over causal extent -------
// A = packed P tiles (stride 128), B = Vt[d][s] (stride 2048). Out f32.
__global__ __launch_bounds__(256, 2) void k_gemm_pv(
    const unsigned short* __restrict__ Pt, const unsigned short* __restrict__ Vt,
    float* __restrict__ out) {
  __shared__ unsigned short As[128 * 64];
  __shared__ unsigned short Bs[128 * 64];
  const int bid = blockIdx.x;
  const int batch = bid >> 7, t = bid & 127;
  const int tm = t >> 3, tn = t & 7;
  const int gm = tm * 128, gn = tn * 128;
  const int tid = threadIdx.x, w = tid >> 6, lane = tid & 63;
  const int wr = w >> 1, wc = w & 1;
  const int srow = lane >> 3;
  const int schunk = (lane & 7) ^ srow;
  const size_t trow = ((size_t)batch * NTRI_ + (tm * (tm + 1)) / 2) * 16384;
  const unsigned short* Bbase = Vt + (size_t)batch * H_ * S_;
  const int nk = (tm + 1) * 2;

  f32x4 acc[4][4];
#pragma unroll
  for (int i = 0; i < 4; ++i)
#pragma unroll
    for (int j = 0; j < 4; ++j) acc[i][j] = (f32x4)0.0f;

  for (int kt = 0; kt < nk; ++kt) {
    const int ktn = kt >> 1, cin = (kt & 1) * 64;
#pragma unroll
    for (int i = 0; i < 4; ++i) {
      const int row = w * 32 + i * 8 + srow;
      __builtin_amdgcn_global_load_lds(
          (const __attribute__((address_space(1))) unsigned int*)(Pt + trow + (size_t)ktn * 16384 + (size_t)row * 128 + cin + schunk * 8),
          (__attribute__((address_space(3))) unsigned int*)(As + (w * 32 + i * 8) * 64),
          16, 0, 0);
      __builtin_amdgcn_global_load_lds(
          (const __attribute__((address_space(1))) unsigned int*)(Bbase + (size_t)(gn + row) * S_ + kt * 64 + schunk * 8),
          (__attribute__((address_space(3))) unsigned int*)(Bs + (w * 32 + i * 8) * 64),
          16, 0, 0);
    }
    __syncthreads();
#pragma unroll
    for (int ks = 0; ks < 2; ++ks) {
      bf16x8 af[4], bfrag[4];
#pragma unroll
      for (int mt = 0; mt < 4; ++mt) {
        const int r16 = wr * 64 + mt * 16 + (lane & 15);
        const int ch = (ks * 4 + (lane >> 4)) ^ (r16 & 7);
        af[mt] = *reinterpret_cast<const bf16x8*>(&As[r16 * 64 + ch * 8]);
      }
#pragma unroll
      for (int nt = 0; nt < 4; ++nt) {
        const int c16 = wc * 64 + nt * 16 + (lane & 15);
        const int ch = (ks * 4 + (lane >> 4)) ^ (c16 & 7);
        bfrag[nt] = *reinterpret_cast<const bf16x8*>(&Bs[c16 * 64 + ch * 8]);
      }
#pragma unroll
      for (int mt = 0; mt < 4; ++mt)
#pragma unroll
        for (int nt = 0; nt < 4; ++nt)
          acc[mt][nt] = __builtin_amdgcn_mfma_f32_16x16x32_bf16(
              af[mt], bfrag[nt], acc[mt][nt], 0, 0, 0);
    }
    __syncthreads();
  }

#pragma unroll
  for (int mt = 0; mt < 4; ++mt) {
#pragma unroll
    for (int nt = 0; nt < 4; ++nt) {
      const int row0 = gm + wr * 64 + mt * 16 + (lane >> 4) * 4;
      const int col = gn + wc * 64 + nt * 16 + (lane & 15);
#pragma unroll
      for (int r = 0; r < 4; ++r)
        out[(size_t)batch * S_ * H_ + (size_t)(row0 + r) * H_ + col] = acc[mt][nt][r];
    }
  }
}

extern "C" void kernel_launch(void* const* d_in, const int* in_sizes, int n_in,
                              void* d_out, int out_size, void* d_ws, size_t ws_size,
                              hipStream_t stream) {
  const float* x  = (const float*)d_in[0];
  const float* Wq = (const float*)d_in[1];
  const float* bq = (const float*)d_in[2];
  const float* Wk = (const float*)d_in[3];
  const float* bk = (const float*)d_in[4];
  const float* Wv = (const float*)d_in[5];
  const float* bv = (const float*)d_in[6];
  float* out = (float*)d_out;

  // ws layout (bf16 elems), total 36,700,160 el = 73.4 MB (== round-1 proven):
  //   Qb [0, 8.39M) | Kb | Vt | X at 25.17M:
  //   X region (11.53M el) holds xb(8.39M)+Wt(3.15M) during QKV phase,
  //   then is reused as packed tri score/P buffer Ptri (8.91M el).
  unsigned short* Qb = (unsigned short*)d_ws;
  unsigned short* Kb = Qb + (size_t)M_ * H_;
  unsigned short* Vt = Kb + (size_t)M_ * H_;
  unsigned short* Xr = Vt + (size_t)M_ * H_;
  unsigned short* xb = Xr;
  unsigned short* Wt = Xr + (size_t)M_ * E_;
  unsigned short* Pt = Xr;

  hipLaunchKernelGGL(k_convert_x, dim3(M_ * E_ / 1024), dim3(256), 0, stream, x, xb);
  hipLaunchKernelGGL(k_transpose_w, dim3(32, 32, 3), dim3(32, 8), 0, stream, Wq, Wk, Wv, Wt);
  hipLaunchKernelGGL(k_gemm_qkv, dim3(1536), dim3(256), 0, stream,
                     xb, Wt, bq, bk, bv, Qb, Kb, Vt);
  hipLaunchKernelGGL(k_gemm_scores, dim3(1024), dim3(256), 0, stream, Qb, Kb, Pt);
  hipLaunchKernelGGL(k_softmax, dim3(2048), dim3(256), 0, stream, Pt);
  hipLaunchKernelGGL(k_gemm_pv, dim3(512), dim3(256), 0, stream, Pt, Vt, out);
}